// Round 11
// baseline (92.511 us; speedup 1.0000x reference)
//
#include <hip/hip_runtime.h>

// Problem constants
#define BATCH 1024
#define RR    49        // 7*7 spatial
#define SP    12544     // 256*49 per-batch patch elems; also FLAT
#define KVALID 625      // nonzero correlation outputs per batch
#define KPAD   640      // padded K for GEMM1
#define REP_N  1024

typedef __attribute__((ext_vector_type(4))) float f32x4;
typedef __attribute__((ext_vector_type(8))) short s16x8;   // 8 bf16 (4 VGPRs)

// ---- bf16 split helpers (RNE) ----
__device__ __forceinline__ unsigned short f2bf_rne(float f) {
    unsigned int u = __float_as_uint(f);
    unsigned int r = u + 0x7FFFu + ((u >> 16) & 1u);
    return (unsigned short)(r >> 16);
}
__device__ __forceinline__ float bf2f(unsigned short h) {
    return __uint_as_float(((unsigned int)h) << 16);
}
__device__ __forceinline__ void split2(float v, unsigned short& h, unsigned short& l) {
    h = f2bf_rne(v);
    l = f2bf_rne(v - bf2f(h));
}
// Pack two floats to bf16 pair (verified numerically R4-R10).
__device__ __forceinline__ unsigned int cvtpk_bf16(float a, float b) {
    unsigned int r;
    asm("v_cvt_pk_bf16_f32 %0, %1, %2" : "=v"(r) : "v"(a), "v"(b));
    return r;
}
// Split 8 floats -> hi/lo s16x8 fragments.
__device__ __forceinline__ void cvt8(const float* v, s16x8& hv, s16x8& lv) {
    unsigned int* hp = (unsigned int*)&hv;
    unsigned int* lp = (unsigned int*)&lv;
    #pragma unroll
    for (int i = 0; i < 4; ++i) {
        float v0 = v[2 * i], v1 = v[2 * i + 1];
        unsigned int ph = cvtpk_bf16(v0, v1);
        float h0 = __uint_as_float(ph << 16);
        float h1 = __uint_as_float(ph & 0xFFFF0000u);
        unsigned int pl = cvtpk_bf16(v0 - h0, v1 - h1);
        hp[i] = ph; lp[i] = pl;
    }
}

// Decode index u in [0,25) -> (i, d), i,d in [0,7), i+d even.
__device__ __forceinline__ void dec25(int u, int& i, int& d) {
    int ii = (u >= 4) + (u >= 7) + (u >= 11) + (u >= 14) + (u >= 18) + (u >= 21);
    int cum = (7 * ii + 1) >> 1;
    i = ii;
    d = 2 * (u - cum) + (ii & 1);
}
// Encode (i,d) -> [0,25), inverse of dec25.
__device__ __forceinline__ int enc25(int i, int d) {
    return ((7 * i + 1) >> 1) + ((d - (i & 1)) >> 1);
}

// Compact index a in [0,640) -> flat column into W1's FLAT dim (a>=625 unused).
__device__ __forceinline__ int kflat_of(int a) {
    int ar = a / 25, ac = a % 25;
    int i, dy, j, dx;
    dec25(ar, i, dy);
    dec25(ac, j, dx);
    int pi = (dy + 16 - i) >> 1;
    int pj = (dx + 16 - j) >> 1;
    return (pi * 16 + pj) * 49 + i * 7 + j;
}

#define MM(d, a, b) d = __builtin_amdgcn_mfma_f32_16x16x32_bf16(a, b, d, 0, 0, 0)

// ---------------------------------------------------------------------------
// Kernel 1: correlation via parity-block-diagonal Gram (compute verified R9),
// with LINEAR LDS staging: the LDS tile is a byte-for-byte copy of the global
// [64ch][49s] chunk, written as identity float4 -> ds_write_b128 (ZERO address
// math — this removes the ~900 VALU/thread div/mod scatter tax of R9/R10).
// Fragment reads use natural stride-49: <=2-way bank aliasing (free).
// 4 chunks of 64 channels, register prefetch of chunk cc+1 under compute.
// ---------------------------------------------------------------------------
__global__ __launch_bounds__(256) void corr_parity_kernel(
    const float* __restrict__ p1, const float* __restrict__ p2,
    unsigned short* __restrict__ xh, unsigned short* __restrict__ xl)
{
    __shared__ float4 T1[784];             // 12.25 KB, linear [64][49] fp32
    __shared__ float4 T2[784];
    __shared__ unsigned short SXh[KPAD];   // compact output staging
    __shared__ unsigned short SXl[KPAD];

    const int b = blockIdx.x;
    const int t = threadIdx.x;
    const float* P1 = p1 + (size_t)b * SP;
    const float* P2 = p2 + (size_t)b * SP;
    const float* Tf1 = (const float*)T1;
    const float* Tf2 = (const float*)T2;

    const int wv   = t >> 6;
    const int lane = t & 63;
    const int fr   = lane & 15;        // class-pos index (A row / B col)
    const int fg   = (lane >> 4) * 8;  // k-offset within 32-chunk

    // class geometry: ci,cj = parities
    const int ci = wv >> 1, cj = wv & 1;
    const int nj = 4 - cj;
    const int clsN = (4 - ci) * nj;          // 16 / 12 / 12 / 9
    const int pr = (fr < clsN) ? fr : 0;
    const int sPos = (2 * (pr / nj) + ci) * 7 + (2 * (pr % nj) + cj);

    // zero output staging
    for (int i = t; i < KPAD; i += 256) { SXh[i] = 0; SXl[i] = 0; }

    // ---- prefetch chunk 0: 784 float4 per tensor, contiguous
    float4 f1[4], f2[4];
    #pragma unroll
    for (int q = 0; q < 4; ++q) {
        const int qi = t + q * 256;
        if (qi < 784) {
            f1[q] = ((const float4*)P1)[qi];
            f2[q] = ((const float4*)P2)[qi];
        }
    }

    f32x4 acc = {};

    for (int cc = 0; cc < 4; ++cc) {
        __syncthreads();   // previous chunk's readers done
        // identity copy into LDS: same index, b128 writes, no address math
        #pragma unroll
        for (int q = 0; q < 4; ++q) {
            const int qi = t + q * 256;
            if (qi < 784) { T1[qi] = f1[q]; T2[qi] = f2[q]; }
        }
        __syncthreads();   // tiles ready

        // issue next chunk's loads; latency hides under compute
        if (cc < 3) {
            const float4* G1 = (const float4*)(P1 + (cc + 1) * 3136);
            const float4* G2 = (const float4*)(P2 + (cc + 1) * 3136);
            #pragma unroll
            for (int q = 0; q < 4; ++q) {
                const int qi = t + q * 256;
                if (qi < 784) { f1[q] = G1[qi]; f2[q] = G2[qi]; }
            }
        }

        // compute: 2 k-steps x (16 ds_read_b32 + 2 cvt8 + 3 MFMA)
        #pragma unroll
        for (int ks = 0; ks < 2; ++ks) {
            const int kb = (ks * 32 + fg) * RR + sPos;
            float av[8], bv[8];
            #pragma unroll
            for (int i = 0; i < 8; ++i) {
                av[i] = Tf1[kb + i * RR];
                bv[i] = Tf2[kb + i * RR];
            }
            s16x8 ah, al, bh, bl;
            cvt8(av, ah, al);
            cvt8(bv, bh, bl);
            MM(acc, ah, bh);
            MM(acc, ah, bl);
            MM(acc, al, bh);
        }
    }

    // Epilogue (verified R9): C/D col = lane&15, row = 4*(lane>>4)+r.
    const int arow = (lane >> 4) * 4;
    if (fr < clsN) {
        const int dy = 2 * (fr / nj) + ci;
        const int dx = 2 * (fr % nj) + cj;
        #pragma unroll
        for (int r = 0; r < 4; ++r) {
            const int rowp = arow + r;
            if (rowp < clsN) {
                const int i1 = 2 * (rowp / nj) + ci;
                const int j1 = 2 * (rowp % nj) + cj;
                const int aidx = enc25(i1, dy) * 25 + enc25(j1, dx);
                unsigned short hh, ll;
                split2(acc[r], hh, ll);
                SXh[aidx] = hh; SXl[aidx] = ll;
            }
        }
    }
    __syncthreads();

    unsigned int* rh = (unsigned int*)(xh + (size_t)b * KPAD);
    unsigned int* rl = (unsigned int*)(xl + (size_t)b * KPAD);
    const unsigned int* sh = (const unsigned int*)SXh;
    const unsigned int* sl = (const unsigned int*)SXl;
    for (int i = t; i < KPAD / 2; i += 256) { rh[i] = sh[i]; rl[i] = sl[i]; }
}

// ---------------------------------------------------------------------------
// Merged weight prep: blocks [0,2560) gather+split W1; [2560,3584) split W2.
// ---------------------------------------------------------------------------
__global__ __launch_bounds__(256) void prep_weights_kernel(
    const float* __restrict__ W1, const float* __restrict__ W2,
    unsigned short* __restrict__ w1h, unsigned short* __restrict__ w1l,
    unsigned short* __restrict__ w2h, unsigned short* __restrict__ w2l)
{
    const int bid = blockIdx.x;
    if (bid < 2560) {
        int idx = bid * 256 + threadIdx.x;   // over REP_N*KPAD
        int n = idx / KPAD, a = idx - n * KPAD;
        float v = 0.f;
        if (a < KVALID) v = W1[(size_t)n * SP + kflat_of(a)];
        unsigned short h, l;
        split2(v, h, l);
        w1h[idx] = h; w1l[idx] = l;
    } else {
        int idx = ((bid - 2560) * 256 + threadIdx.x) * 4;   // over REP_N*REP_N
        float4 v = *(const float4*)&W2[idx];
        unsigned short h0, l0, h1, l1, h2, l2, h3, l3;
        split2(v.x, h0, l0); split2(v.y, h1, l1);
        split2(v.z, h2, l2); split2(v.w, h3, l3);
        *(ushort4*)&w2h[idx] = make_ushort4(h0, h1, h2, h3);
        *(ushort4*)&w2l[idx] = make_ushort4(l0, l1, l2, l3);
    }
}

// ---------------------------------------------------------------------------
// MFMA GEMM: Y[m,n] = relu( sum_k X[m,k]*W[n,k] + bias[n] )
// X,W as bf16 hi/lo planes; products hh + hl + lh. 64x64 tile, BK=64,
// 4 waves (2x2), each wave 32x32 = 2x2 16x16x32 fragments.
// ---------------------------------------------------------------------------
template<bool SPLIT_OUT>
__global__ __launch_bounds__(256) void gemm_mfma(
    const unsigned short* __restrict__ Xh, const unsigned short* __restrict__ Xl, int ldx,
    const unsigned short* __restrict__ Wh, const unsigned short* __restrict__ Wl, int ldw,
    const float* __restrict__ bias, int K,
    float* __restrict__ Yf, unsigned short* __restrict__ Yh, unsigned short* __restrict__ Yl,
    int ldy)
{
    __shared__ unsigned short As[2][64][72];
    __shared__ unsigned short Bs[2][64][72];

    const int t = threadIdx.x;
    const int m_base = blockIdx.y * 64;
    const int n_base = blockIdx.x * 64;

    const int trow = t >> 2;
    const int tc   = (t & 3) * 8;

    const unsigned short* xh_p = Xh + (size_t)(m_base + trow) * ldx + tc;
    const unsigned short* xl_p = Xl + (size_t)(m_base + trow) * ldx + tc;
    const unsigned short* wh_p = Wh + (size_t)(n_base + trow) * ldw + tc;
    const unsigned short* wl_p = Wl + (size_t)(n_base + trow) * ldw + tc;

    const int wv   = t >> 6;
    const int lane = t & 63;
    const int wr = (wv >> 1) * 32;
    const int wc = (wv & 1) * 32;
    const int fr = lane & 15;
    const int fg = (lane >> 4) * 8;

    f32x4 acc00 = {}, acc01 = {}, acc10 = {}, acc11 = {};

    for (int k0 = 0; k0 < K; k0 += 64) {
        s16x8 vxh0 = *(const s16x8*)(xh_p + k0);
        s16x8 vxh1 = *(const s16x8*)(xh_p + k0 + 32);
        s16x8 vxl0 = *(const s16x8*)(xl_p + k0);
        s16x8 vxl1 = *(const s16x8*)(xl_p + k0 + 32);
        s16x8 vwh0 = *(const s16x8*)(wh_p + k0);
        s16x8 vwh1 = *(const s16x8*)(wh_p + k0 + 32);
        s16x8 vwl0 = *(const s16x8*)(wl_p + k0);
        s16x8 vwl1 = *(const s16x8*)(wl_p + k0 + 32);
        __syncthreads();
        *(s16x8*)&As[0][trow][tc]      = vxh0;
        *(s16x8*)&As[0][trow][tc + 32] = vxh1;
        *(s16x8*)&As[1][trow][tc]      = vxl0;
        *(s16x8*)&As[1][trow][tc + 32] = vxl1;
        *(s16x8*)&Bs[0][trow][tc]      = vwh0;
        *(s16x8*)&Bs[0][trow][tc + 32] = vwh1;
        *(s16x8*)&Bs[1][trow][tc]      = vwl0;
        *(s16x8*)&Bs[1][trow][tc + 32] = vwl1;
        __syncthreads();

        #pragma unroll
        for (int ks = 0; ks < 2; ++ks) {
            const int ko = ks * 32 + fg;
            s16x8 ah0 = *(const s16x8*)&As[0][wr + fr][ko];
            s16x8 ah1 = *(const s16x8*)&As[0][wr + 16 + fr][ko];
            s16x8 al0 = *(const s16x8*)&As[1][wr + fr][ko];
            s16x8 al1 = *(const s16x8*)&As[1][wr + 16 + fr][ko];
            s16x8 bh0 = *(const s16x8*)&Bs[0][wc + fr][ko];
            s16x8 bh1 = *(const s16x8*)&Bs[0][wc + 16 + fr][ko];
            s16x8 bl0 = *(const s16x8*)&Bs[1][wc + fr][ko];
            s16x8 bl1 = *(const s16x8*)&Bs[1][wc + 16 + fr][ko];

            MM(acc00, ah0, bh0); MM(acc00, ah0, bl0); MM(acc00, al0, bh0);
            MM(acc01, ah0, bh1); MM(acc01, ah0, bl1); MM(acc01, al0, bh1);
            MM(acc10, ah1, bh0); MM(acc10, ah1, bl0); MM(acc10, al1, bh0);
            MM(acc11, ah1, bh1); MM(acc11, ah1, bl1); MM(acc11, al1, bh1);
        }
    }

    const int arow = (lane >> 4) * 4;
    #pragma unroll
    for (int nf = 0; nf < 2; ++nf) {
        const int col = n_base + wc + nf * 16 + fr;
        const float bv = bias[col];
        #pragma unroll
        for (int mf = 0; mf < 2; ++mf) {
            const f32x4 a = (nf == 0) ? (mf == 0 ? acc00 : acc10)
                                      : (mf == 0 ? acc01 : acc11);
            #pragma unroll
            for (int r = 0; r < 4; ++r) {
                const int row = m_base + wr + mf * 16 + arow + r;
                float v = fmaxf(a[r] + bv, 0.f);
                if (SPLIT_OUT) {
                    unsigned short h, l;
                    split2(v, h, l);
                    Yh[(size_t)row * ldy + col] = h;
                    Yl[(size_t)row * ldy + col] = l;
                } else {
                    Yf[(size_t)row * ldy + col] = v;
                }
            }
        }
    }
}

// ---------------------------------------------------------------------------
// Head: out[b,:] = h2[b,:] @ W3.T + b3
// ---------------------------------------------------------------------------
__global__ __launch_bounds__(256) void head_kernel(
    const float* __restrict__ h2, const float* __restrict__ W3,
    const float* __restrict__ b3, float* __restrict__ out)
{
    const int b = blockIdx.x;
    const int t = threadIdx.x;
    const float* row = h2 + (size_t)b * REP_N;

    float a0 = 0.f, a1 = 0.f, a2 = 0.f, a3 = 0.f;
    for (int k = t; k < REP_N; k += 256) {
        float x = row[k];
        a0 = fmaf(x, W3[k],             a0);
        a1 = fmaf(x, W3[REP_N + k],     a1);
        a2 = fmaf(x, W3[2 * REP_N + k], a2);
        a3 = fmaf(x, W3[3 * REP_N + k], a3);
    }
    #pragma unroll
    for (int off = 32; off > 0; off >>= 1) {
        a0 += __shfl_down(a0, off);
        a1 += __shfl_down(a1, off);
        a2 += __shfl_down(a2, off);
        a3 += __shfl_down(a3, off);
    }
    __shared__ float red[4][4];
    int wid = t >> 6, lane = t & 63;
    if (lane == 0) { red[wid][0] = a0; red[wid][1] = a1; red[wid][2] = a2; red[wid][3] = a3; }
    __syncthreads();
    if (t < 4) {
        out[b * 4 + t] = red[0][t] + red[1][t] + red[2][t] + red[3][t] + b3[t];
    }
}

extern "C" void kernel_launch(void* const* d_in, const int* in_sizes, int n_in,
                              void* d_out, int out_size, void* d_ws, size_t ws_size,
                              hipStream_t stream) {
    const float* p1 = (const float*)d_in[0];
    const float* p2 = (const float*)d_in[1];
    const float* W1 = (const float*)d_in[2];
    const float* b1 = (const float*)d_in[3];
    const float* W2 = (const float*)d_in[4];
    const float* b2 = (const float*)d_in[5];
    const float* W3 = (const float*)d_in[6];
    const float* b3 = (const float*)d_in[7];
    float* out = (float*)d_out;

    char* ws = (char*)d_ws;
    unsigned short* xh  = (unsigned short*)(ws + 0);         // 1.31 MB
    unsigned short* xl  = (unsigned short*)(ws + 1310720);   // 1.31 MB
    unsigned short* w1h = (unsigned short*)(ws + 2621440);   // 1.31 MB
    unsigned short* w1l = (unsigned short*)(ws + 3932160);   // 1.31 MB
    float*          h2  = (float*)(ws + 0);                  // 4.19 MB (reuse after GEMM1)
    unsigned short* h1h = (unsigned short*)(ws + 5242880);   // 2.10 MB
    unsigned short* h1l = (unsigned short*)(ws + 7340032);   // 2.10 MB
    unsigned short* w2h = (unsigned short*)(ws + 9437184);   // 2.10 MB
    unsigned short* w2l = (unsigned short*)(ws + 11534336);  // 2.10 MB

    corr_parity_kernel<<<BATCH, 256, 0, stream>>>(p1, p2, xh, xl);
    prep_weights_kernel<<<3584, 256, 0, stream>>>(W1, W2, w1h, w1l, w2h, w2l);

    gemm_mfma<true><<<dim3(16, 16), 256, 0, stream>>>(
        xh, xl, KPAD, w1h, w1l, KPAD, b1, KPAD,
        (float*)nullptr, h1h, h1l, REP_N);

    gemm_mfma<false><<<dim3(16, 16), 256, 0, stream>>>(
        h1h, h1l, REP_N, w2h, w2l, REP_N, b2, REP_N,
        h2, (unsigned short*)nullptr, (unsigned short*)nullptr, REP_N);

    head_kernel<<<BATCH, 256, 0, stream>>>(h2, W3, b3, out);
}

// Round 12
// 64.518 us; speedup vs baseline: 1.4339x; 1.4339x over previous
//
#include <hip/hip_runtime.h>

// Problem constants
#define BATCH 1024
#define RR    49        // 7*7 spatial
#define SP    12544     // 256*49 per-batch patch elems; also FLAT
#define KVALID 625      // nonzero correlation outputs per batch
#define KPAD   640      // padded K for GEMM1
#define REP_N  1024

typedef __attribute__((ext_vector_type(4))) float f32x4;
typedef __attribute__((ext_vector_type(8))) short s16x8;   // 8 bf16 (4 VGPRs)

// ---- bf16 split helpers (RNE) ----
__device__ __forceinline__ unsigned short f2bf_rne(float f) {
    unsigned int u = __float_as_uint(f);
    unsigned int r = u + 0x7FFFu + ((u >> 16) & 1u);
    return (unsigned short)(r >> 16);
}
__device__ __forceinline__ float bf2f(unsigned short h) {
    return __uint_as_float(((unsigned int)h) << 16);
}
__device__ __forceinline__ void split2(float v, unsigned short& h, unsigned short& l) {
    h = f2bf_rne(v);
    l = f2bf_rne(v - bf2f(h));
}
// Pack two floats to bf16 pair (verified numerically R4-R11).
__device__ __forceinline__ unsigned int cvtpk_bf16(float a, float b) {
    unsigned int r;
    asm("v_cvt_pk_bf16_f32 %0, %1, %2" : "=v"(r) : "v"(a), "v"(b));
    return r;
}
// Split 8 floats -> hi/lo s16x8 fragments.
__device__ __forceinline__ void cvt8(const float* v, s16x8& hv, s16x8& lv) {
    unsigned int* hp = (unsigned int*)&hv;
    unsigned int* lp = (unsigned int*)&lv;
    #pragma unroll
    for (int i = 0; i < 4; ++i) {
        float v0 = v[2 * i], v1 = v[2 * i + 1];
        unsigned int ph = cvtpk_bf16(v0, v1);
        float h0 = __uint_as_float(ph << 16);
        float h1 = __uint_as_float(ph & 0xFFFF0000u);
        unsigned int pl = cvtpk_bf16(v0 - h0, v1 - h1);
        hp[i] = ph; lp[i] = pl;
    }
}

// Decode index u in [0,25) -> (i, d), i,d in [0,7), i+d even.
__device__ __forceinline__ void dec25(int u, int& i, int& d) {
    int ii = (u >= 4) + (u >= 7) + (u >= 11) + (u >= 14) + (u >= 18) + (u >= 21);
    int cum = (7 * ii + 1) >> 1;
    i = ii;
    d = 2 * (u - cum) + (ii & 1);
}
// Encode (i,d) -> [0,25), inverse of dec25.
__device__ __forceinline__ int enc25(int i, int d) {
    return ((7 * i + 1) >> 1) + ((d - (i & 1)) >> 1);
}

// Compact index a in [0,640) -> flat column into W1's FLAT dim (a>=625 unused).
__device__ __forceinline__ int kflat_of(int a) {
    int ar = a / 25, ac = a % 25;
    int i, dy, j, dx;
    dec25(ar, i, dy);
    dec25(ac, j, dx);
    int pi = (dy + 16 - i) >> 1;
    int pj = (dx + 16 - j) >> 1;
    return (pi * 16 + pj) * 49 + i * 7 + j;
}

#define MM(d, a, b) d = __builtin_amdgcn_mfma_f32_16x16x32_bf16(a, b, d, 0, 0, 0)

// ---------------------------------------------------------------------------
// Kernel 1: correlation via parity-block-diagonal Gram (compute verified R9).
// Staging: __builtin_amdgcn_global_load_lds width=16 into DOUBLE-BUFFERED
// linear LDS tiles — identity layout, zero address math, NO prefetch
// registers (R11's spill is structurally impossible). 2-phase pipeline:
// barrier -> issue next chunk's async loads into buf^1 -> compute buf.
// ---------------------------------------------------------------------------
__global__ __launch_bounds__(256) void corr_parity_kernel(
    const float* __restrict__ p1, const float* __restrict__ p2,
    unsigned short* __restrict__ xh, unsigned short* __restrict__ xl)
{
    __shared__ float4 Tb[2][2][832];       // [buf][tensor][13*64] = 53.2 KB
    __shared__ unsigned short SXh[KPAD];   // compact output staging
    __shared__ unsigned short SXl[KPAD];

    const int b = blockIdx.x;
    const int t = threadIdx.x;
    const float* P1 = p1 + (size_t)b * SP;
    const float* P2 = p2 + (size_t)b * SP;

    const int wv   = t >> 6;
    const int lane = t & 63;
    const int fr   = lane & 15;        // class-pos index (A row / B col)
    const int fg   = (lane >> 4) * 8;  // k-offset within 32-chunk

    // class geometry: ci,cj = parities
    const int ci = wv >> 1, cj = wv & 1;
    const int nj = 4 - cj;
    const int clsN = (4 - ci) * nj;          // 16 / 12 / 12 / 9
    const int pr = (fr < clsN) ? fr : 0;
    const int sPos = (2 * (pr / nj) + ci) * 7 + (2 * (pr % nj) + cj);

    // staging role: waves 0,1 -> tensor 0 (p1); waves 2,3 -> tensor 1 (p2)
    const float* PS = (wv < 2) ? P1 : P2;
    const int tens  = wv >> 1;
    const int start = (wv & 1) * 7;          // block range: [0,7) or [7,13)
    const int nb    = (wv & 1) ? 6 : 7;

    // async stage of one 64-channel chunk (3136 floats) into Tb[buf][tens]
    #define STAGE(buf, chunk)                                                  \
        do {                                                                   \
            const int cOff_ = (chunk) * 3136;                                  \
            float4* T_ = &Tb[(buf)][tens][0];                                  \
            _Pragma("unroll")                                                  \
            for (int j_ = 0; j_ < 7; ++j_) {                                   \
                if (j_ < nb) {                                                 \
                    const int bq_  = start + j_;                               \
                    const int src_ = min(bq_ * 64 + lane, 783);                \
                    __builtin_amdgcn_global_load_lds(                          \
                        (const __attribute__((address_space(1))) unsigned int*)\
                            (PS + cOff_ + src_ * 4),                           \
                        (__attribute__((address_space(3))) unsigned int*)      \
                            (T_ + bq_ * 64),                                   \
                        16, 0, 0);                                             \
                }                                                              \
            }                                                                  \
        } while (0)

    // zero output staging (tail 625..639 must be 0)
    for (int i = t; i < KPAD; i += 256) { SXh[i] = 0; SXl[i] = 0; }

    STAGE(0, 0);   // prologue: chunk 0 -> buf 0

    f32x4 acc = {};
    int cur = 0;
    for (int cc = 0; cc < 4; ++cc) {
        __syncthreads();   // drains vmcnt: buf[cur] staged; prev reads done
        if (cc < 3) STAGE(cur ^ 1, cc + 1);   // async loads fly under compute

        const float* Tf1 = (const float*)&Tb[cur][0][0];
        const float* Tf2 = (const float*)&Tb[cur][1][0];
        #pragma unroll
        for (int ks = 0; ks < 2; ++ks) {
            const int kb = (ks * 32 + fg) * RR + sPos;
            float av[8], bv[8];
            #pragma unroll
            for (int i = 0; i < 8; ++i) {
                av[i] = Tf1[kb + i * RR];
                bv[i] = Tf2[kb + i * RR];
            }
            s16x8 ah, al, bh, bl;
            cvt8(av, ah, al);
            cvt8(bv, bh, bl);
            MM(acc, ah, bh);
            MM(acc, ah, bl);
            MM(acc, al, bh);
        }
        cur ^= 1;
    }
    #undef STAGE

    // Epilogue (verified R9): C/D col = lane&15, row = 4*(lane>>4)+r.
    const int arow = (lane >> 4) * 4;
    if (fr < clsN) {
        const int dy = 2 * (fr / nj) + ci;
        const int dx = 2 * (fr % nj) + cj;
        #pragma unroll
        for (int r = 0; r < 4; ++r) {
            const int rowp = arow + r;
            if (rowp < clsN) {
                const int i1 = 2 * (rowp / nj) + ci;
                const int j1 = 2 * (rowp % nj) + cj;
                const int aidx = enc25(i1, dy) * 25 + enc25(j1, dx);
                unsigned short hh, ll;
                split2(acc[r], hh, ll);
                SXh[aidx] = hh; SXl[aidx] = ll;
            }
        }
    }
    __syncthreads();

    unsigned int* rh = (unsigned int*)(xh + (size_t)b * KPAD);
    unsigned int* rl = (unsigned int*)(xl + (size_t)b * KPAD);
    const unsigned int* sh = (const unsigned int*)SXh;
    const unsigned int* sl = (const unsigned int*)SXl;
    for (int i = t; i < KPAD / 2; i += 256) { rh[i] = sh[i]; rl[i] = sl[i]; }
}

// ---------------------------------------------------------------------------
// Merged weight prep: blocks [0,2560) gather+split W1; [2560,3584) split W2.
// ---------------------------------------------------------------------------
__global__ __launch_bounds__(256) void prep_weights_kernel(
    const float* __restrict__ W1, const float* __restrict__ W2,
    unsigned short* __restrict__ w1h, unsigned short* __restrict__ w1l,
    unsigned short* __restrict__ w2h, unsigned short* __restrict__ w2l)
{
    const int bid = blockIdx.x;
    if (bid < 2560) {
        int idx = bid * 256 + threadIdx.x;   // over REP_N*KPAD
        int n = idx / KPAD, a = idx - n * KPAD;
        float v = 0.f;
        if (a < KVALID) v = W1[(size_t)n * SP + kflat_of(a)];
        unsigned short h, l;
        split2(v, h, l);
        w1h[idx] = h; w1l[idx] = l;
    } else {
        int idx = ((bid - 2560) * 256 + threadIdx.x) * 4;   // over REP_N*REP_N
        float4 v = *(const float4*)&W2[idx];
        unsigned short h0, l0, h1, l1, h2, l2, h3, l3;
        split2(v.x, h0, l0); split2(v.y, h1, l1);
        split2(v.z, h2, l2); split2(v.w, h3, l3);
        *(ushort4*)&w2h[idx] = make_ushort4(h0, h1, h2, h3);
        *(ushort4*)&w2l[idx] = make_ushort4(l0, l1, l2, l3);
    }
}

// ---------------------------------------------------------------------------
// MFMA GEMM: Y[m,n] = relu( sum_k X[m,k]*W[n,k] + bias[n] )
// X,W as bf16 hi/lo planes; products hh + hl + lh. 64x64 tile, BK=64,
// 4 waves (2x2), each wave 32x32 = 2x2 16x16x32 fragments.
// ---------------------------------------------------------------------------
template<bool SPLIT_OUT>
__global__ __launch_bounds__(256) void gemm_mfma(
    const unsigned short* __restrict__ Xh, const unsigned short* __restrict__ Xl, int ldx,
    const unsigned short* __restrict__ Wh, const unsigned short* __restrict__ Wl, int ldw,
    const float* __restrict__ bias, int K,
    float* __restrict__ Yf, unsigned short* __restrict__ Yh, unsigned short* __restrict__ Yl,
    int ldy)
{
    __shared__ unsigned short As[2][64][72];
    __shared__ unsigned short Bs[2][64][72];

    const int t = threadIdx.x;
    const int m_base = blockIdx.y * 64;
    const int n_base = blockIdx.x * 64;

    const int trow = t >> 2;
    const int tc   = (t & 3) * 8;

    const unsigned short* xh_p = Xh + (size_t)(m_base + trow) * ldx + tc;
    const unsigned short* xl_p = Xl + (size_t)(m_base + trow) * ldx + tc;
    const unsigned short* wh_p = Wh + (size_t)(n_base + trow) * ldw + tc;
    const unsigned short* wl_p = Wl + (size_t)(n_base + trow) * ldw + tc;

    const int wv   = t >> 6;
    const int lane = t & 63;
    const int wr = (wv >> 1) * 32;
    const int wc = (wv & 1) * 32;
    const int fr = lane & 15;
    const int fg = (lane >> 4) * 8;

    f32x4 acc00 = {}, acc01 = {}, acc10 = {}, acc11 = {};

    for (int k0 = 0; k0 < K; k0 += 64) {
        s16x8 vxh0 = *(const s16x8*)(xh_p + k0);
        s16x8 vxh1 = *(const s16x8*)(xh_p + k0 + 32);
        s16x8 vxl0 = *(const s16x8*)(xl_p + k0);
        s16x8 vxl1 = *(const s16x8*)(xl_p + k0 + 32);
        s16x8 vwh0 = *(const s16x8*)(wh_p + k0);
        s16x8 vwh1 = *(const s16x8*)(wh_p + k0 + 32);
        s16x8 vwl0 = *(const s16x8*)(wl_p + k0);
        s16x8 vwl1 = *(const s16x8*)(wl_p + k0 + 32);
        __syncthreads();
        *(s16x8*)&As[0][trow][tc]      = vxh0;
        *(s16x8*)&As[0][trow][tc + 32] = vxh1;
        *(s16x8*)&As[1][trow][tc]      = vxl0;
        *(s16x8*)&As[1][trow][tc + 32] = vxl1;
        *(s16x8*)&Bs[0][trow][tc]      = vwh0;
        *(s16x8*)&Bs[0][trow][tc + 32] = vwh1;
        *(s16x8*)&Bs[1][trow][tc]      = vwl0;
        *(s16x8*)&Bs[1][trow][tc + 32] = vwl1;
        __syncthreads();

        #pragma unroll
        for (int ks = 0; ks < 2; ++ks) {
            const int ko = ks * 32 + fg;
            s16x8 ah0 = *(const s16x8*)&As[0][wr + fr][ko];
            s16x8 ah1 = *(const s16x8*)&As[0][wr + 16 + fr][ko];
            s16x8 al0 = *(const s16x8*)&As[1][wr + fr][ko];
            s16x8 al1 = *(const s16x8*)&As[1][wr + 16 + fr][ko];
            s16x8 bh0 = *(const s16x8*)&Bs[0][wc + fr][ko];
            s16x8 bh1 = *(const s16x8*)&Bs[0][wc + 16 + fr][ko];
            s16x8 bl0 = *(const s16x8*)&Bs[1][wc + fr][ko];
            s16x8 bl1 = *(const s16x8*)&Bs[1][wc + 16 + fr][ko];

            MM(acc00, ah0, bh0); MM(acc00, ah0, bl0); MM(acc00, al0, bh0);
            MM(acc01, ah0, bh1); MM(acc01, ah0, bl1); MM(acc01, al0, bh1);
            MM(acc10, ah1, bh0); MM(acc10, ah1, bl0); MM(acc10, al1, bh0);
            MM(acc11, ah1, bh1); MM(acc11, ah1, bl1); MM(acc11, al1, bh1);
        }
    }

    const int arow = (lane >> 4) * 4;
    #pragma unroll
    for (int nf = 0; nf < 2; ++nf) {
        const int col = n_base + wc + nf * 16 + fr;
        const float bv = bias[col];
        #pragma unroll
        for (int mf = 0; mf < 2; ++mf) {
            const f32x4 a = (nf == 0) ? (mf == 0 ? acc00 : acc10)
                                      : (mf == 0 ? acc01 : acc11);
            #pragma unroll
            for (int r = 0; r < 4; ++r) {
                const int row = m_base + wr + mf * 16 + arow + r;
                float v = fmaxf(a[r] + bv, 0.f);
                if (SPLIT_OUT) {
                    unsigned short h, l;
                    split2(v, h, l);
                    Yh[(size_t)row * ldy + col] = h;
                    Yl[(size_t)row * ldy + col] = l;
                } else {
                    Yf[(size_t)row * ldy + col] = v;
                }
            }
        }
    }
}

// ---------------------------------------------------------------------------
// Head: out[b,:] = h2[b,:] @ W3.T + b3
// ---------------------------------------------------------------------------
__global__ __launch_bounds__(256) void head_kernel(
    const float* __restrict__ h2, const float* __restrict__ W3,
    const float* __restrict__ b3, float* __restrict__ out)
{
    const int b = blockIdx.x;
    const int t = threadIdx.x;
    const float* row = h2 + (size_t)b * REP_N;

    float a0 = 0.f, a1 = 0.f, a2 = 0.f, a3 = 0.f;
    for (int k = t; k < REP_N; k += 256) {
        float x = row[k];
        a0 = fmaf(x, W3[k],             a0);
        a1 = fmaf(x, W3[REP_N + k],     a1);
        a2 = fmaf(x, W3[2 * REP_N + k], a2);
        a3 = fmaf(x, W3[3 * REP_N + k], a3);
    }
    #pragma unroll
    for (int off = 32; off > 0; off >>= 1) {
        a0 += __shfl_down(a0, off);
        a1 += __shfl_down(a1, off);
        a2 += __shfl_down(a2, off);
        a3 += __shfl_down(a3, off);
    }
    __shared__ float red[4][4];
    int wid = t >> 6, lane = t & 63;
    if (lane == 0) { red[wid][0] = a0; red[wid][1] = a1; red[wid][2] = a2; red[wid][3] = a3; }
    __syncthreads();
    if (t < 4) {
        out[b * 4 + t] = red[0][t] + red[1][t] + red[2][t] + red[3][t] + b3[t];
    }
}

extern "C" void kernel_launch(void* const* d_in, const int* in_sizes, int n_in,
                              void* d_out, int out_size, void* d_ws, size_t ws_size,
                              hipStream_t stream) {
    const float* p1 = (const float*)d_in[0];
    const float* p2 = (const float*)d_in[1];
    const float* W1 = (const float*)d_in[2];
    const float* b1 = (const float*)d_in[3];
    const float* W2 = (const float*)d_in[4];
    const float* b2 = (const float*)d_in[5];
    const float* W3 = (const float*)d_in[6];
    const float* b3 = (const float*)d_in[7];
    float* out = (float*)d_out;

    char* ws = (char*)d_ws;
    unsigned short* xh  = (unsigned short*)(ws + 0);         // 1.31 MB
    unsigned short* xl  = (unsigned short*)(ws + 1310720);   // 1.31 MB
    unsigned short* w1h = (unsigned short*)(ws + 2621440);   // 1.31 MB
    unsigned short* w1l = (unsigned short*)(ws + 3932160);   // 1.31 MB
    float*          h2  = (float*)(ws + 0);                  // 4.19 MB (reuse after GEMM1)
    unsigned short* h1h = (unsigned short*)(ws + 5242880);   // 2.10 MB
    unsigned short* h1l = (unsigned short*)(ws + 7340032);   // 2.10 MB
    unsigned short* w2h = (unsigned short*)(ws + 9437184);   // 2.10 MB
    unsigned short* w2l = (unsigned short*)(ws + 11534336);  // 2.10 MB

    corr_parity_kernel<<<BATCH, 256, 0, stream>>>(p1, p2, xh, xl);
    prep_weights_kernel<<<3584, 256, 0, stream>>>(W1, W2, w1h, w1l, w2h, w2l);

    gemm_mfma<true><<<dim3(16, 16), 256, 0, stream>>>(
        xh, xl, KPAD, w1h, w1l, KPAD, b1, KPAD,
        (float*)nullptr, h1h, h1l, REP_N);

    gemm_mfma<false><<<dim3(16, 16), 256, 0, stream>>>(
        h1h, h1l, REP_N, w2h, w2l, REP_N, b2, REP_N,
        h2, (unsigned short*)nullptr, (unsigned short*)nullptr, REP_N);

    head_kernel<<<BATCH, 256, 0, stream>>>(h2, W3, b3, out);
}

// Round 13
// 62.590 us; speedup vs baseline: 1.4780x; 1.0308x over previous
//
#include <hip/hip_runtime.h>

// Problem constants
#define BATCH 1024
#define RR    49        // 7*7 spatial
#define SP    12544     // 256*49 per-batch patch elems; also FLAT
#define KVALID 625      // nonzero correlation outputs per batch
#define KPAD   640      // padded K for GEMM1
#define REP_N  1024

typedef __attribute__((ext_vector_type(4))) float f32x4;
typedef __attribute__((ext_vector_type(8))) short s16x8;   // 8 bf16 (4 VGPRs)

// ---- bf16 split helpers (RNE) ----
__device__ __forceinline__ unsigned short f2bf_rne(float f) {
    unsigned int u = __float_as_uint(f);
    unsigned int r = u + 0x7FFFu + ((u >> 16) & 1u);
    return (unsigned short)(r >> 16);
}
__device__ __forceinline__ float bf2f(unsigned short h) {
    return __uint_as_float(((unsigned int)h) << 16);
}
__device__ __forceinline__ void split2(float v, unsigned short& h, unsigned short& l) {
    h = f2bf_rne(v);
    l = f2bf_rne(v - bf2f(h));
}
// Pack two floats to bf16 pair (verified numerically R4-R12).
__device__ __forceinline__ unsigned int cvtpk_bf16(float a, float b) {
    unsigned int r;
    asm("v_cvt_pk_bf16_f32 %0, %1, %2" : "=v"(r) : "v"(a), "v"(b));
    return r;
}
// Split 8 floats -> hi/lo s16x8 fragments.
__device__ __forceinline__ void cvt8(const float* v, s16x8& hv, s16x8& lv) {
    unsigned int* hp = (unsigned int*)&hv;
    unsigned int* lp = (unsigned int*)&lv;
    #pragma unroll
    for (int i = 0; i < 4; ++i) {
        float v0 = v[2 * i], v1 = v[2 * i + 1];
        unsigned int ph = cvtpk_bf16(v0, v1);
        float h0 = __uint_as_float(ph << 16);
        float h1 = __uint_as_float(ph & 0xFFFF0000u);
        unsigned int pl = cvtpk_bf16(v0 - h0, v1 - h1);
        hp[i] = ph; lp[i] = pl;
    }
}

// Decode index u in [0,25) -> (i, d), i,d in [0,7), i+d even.
__device__ __forceinline__ void dec25(int u, int& i, int& d) {
    int ii = (u >= 4) + (u >= 7) + (u >= 11) + (u >= 14) + (u >= 18) + (u >= 21);
    int cum = (7 * ii + 1) >> 1;
    i = ii;
    d = 2 * (u - cum) + (ii & 1);
}
// Encode (i,d) -> [0,25), inverse of dec25.
__device__ __forceinline__ int enc25(int i, int d) {
    return ((7 * i + 1) >> 1) + ((d - (i & 1)) >> 1);
}

// Compact index a in [0,640) -> flat column into W1's FLAT dim (a>=625 unused).
__device__ __forceinline__ int kflat_of(int a) {
    int ar = a / 25, ac = a % 25;
    int i, dy, j, dx;
    dec25(ar, i, dy);
    dec25(ac, j, dx);
    int pi = (dy + 16 - i) >> 1;
    int pj = (dx + 16 - j) >> 1;
    return (pi * 16 + pj) * 49 + i * 7 + j;
}

#define MM(d, a, b) d = __builtin_amdgcn_mfma_f32_16x16x32_bf16(a, b, d, 0, 0, 0)

// ---------------------------------------------------------------------------
// MEGA kernel: corr (parity Gram, verified R9/R12) + W1/W2 prep fused.
// Block routing (interleaved so corr and prep co-reside on CUs from t=0):
//   bid < 2048, even  -> corr batch bid/2
//   bid < 2048, odd   -> W1-prep block bid/2          (first 1024 of 2560)
//   bid >= 2048       -> prep block 1024 + (bid-2048) (rest of W1, then W2)
// corr: 8 half-chunks (32 ch) double-buffered via global_load_lds width=16;
// LDS 30.6 KB -> 5 blocks/CU so prep blocks backfill idle slots.
// ---------------------------------------------------------------------------
__global__ __launch_bounds__(256) void corr_prep_kernel(
    const float* __restrict__ p1, const float* __restrict__ p2,
    const float* __restrict__ W1, const float* __restrict__ W2,
    unsigned short* __restrict__ xh, unsigned short* __restrict__ xl,
    unsigned short* __restrict__ w1h, unsigned short* __restrict__ w1l,
    unsigned short* __restrict__ w2h, unsigned short* __restrict__ w2l)
{
    __shared__ float4 Tb[2][2][448];       // [buf][tensor][7*64] = 28 KB
    __shared__ unsigned short SXh[KPAD];   // compact output staging
    __shared__ unsigned short SXl[KPAD];

    const int bid = blockIdx.x;
    const int t   = threadIdx.x;

    bool isCorr = false;
    int cid = 0, pid = 0;
    if (bid < 2048) {
        if ((bid & 1) == 0) { isCorr = true; cid = bid >> 1; }
        else                { pid = bid >> 1; }
    } else {
        pid = 1024 + (bid - 2048);
    }

    if (!isCorr) {
        // ---- weight prep branch (block-uniform) ----
        if (pid < 2560) {
            int idx = pid * 256 + t;             // over REP_N*KPAD
            int n = idx / KPAD, a = idx - n * KPAD;
            float v = 0.f;
            if (a < KVALID) v = W1[(size_t)n * SP + kflat_of(a)];
            unsigned short h, l;
            split2(v, h, l);
            w1h[idx] = h; w1l[idx] = l;
        } else {
            int idx = ((pid - 2560) * 256 + t) * 4;   // over REP_N*REP_N
            float4 v = *(const float4*)&W2[idx];
            unsigned short h0, l0, h1, l1, h2, l2, h3, l3;
            split2(v.x, h0, l0); split2(v.y, h1, l1);
            split2(v.z, h2, l2); split2(v.w, h3, l3);
            *(ushort4*)&w2h[idx] = make_ushort4(h0, h1, h2, h3);
            *(ushort4*)&w2l[idx] = make_ushort4(l0, l1, l2, l3);
        }
        return;
    }

    // ---- corr branch ----
    const float* P1 = p1 + (size_t)cid * SP;
    const float* P2 = p2 + (size_t)cid * SP;

    const int wv   = t >> 6;
    const int lane = t & 63;
    const int fr   = lane & 15;        // class-pos index (A row / B col)
    const int fg   = (lane >> 4) * 8;  // k-offset within 32-row tile

    // parity-class geometry
    const int ci = wv >> 1, cj = wv & 1;
    const int nj = 4 - cj;
    const int clsN = (4 - ci) * nj;          // 16 / 12 / 12 / 9
    const int pr = (fr < clsN) ? fr : 0;
    const int sPos = (2 * (pr / nj) + ci) * 7 + (2 * (pr % nj) + cj);

    // staging role: waves 0,1 -> p1; waves 2,3 -> p2. Each half-chunk is
    // 32ch*49 = 1568 floats = 392 float4; wave pair splits 0..3 / 4..6.
    const float* PS = (wv < 2) ? P1 : P2;
    const int tens  = wv >> 1;
    const int start = (wv & 1) * 4;
    const int nb    = (wv & 1) ? 3 : 4;

    #define STAGE(buf, hc)                                                     \
        do {                                                                   \
            const int off_ = (hc) * 1568;                                      \
            float4* T_ = &Tb[(buf)][tens][0];                                  \
            _Pragma("unroll")                                                  \
            for (int j_ = 0; j_ < 4; ++j_) {                                   \
                if (j_ < nb) {                                                 \
                    const int bq_  = start + j_;                               \
                    const int src_ = min(bq_ * 64 + lane, 391);                \
                    __builtin_amdgcn_global_load_lds(                          \
                        (const __attribute__((address_space(1))) unsigned int*)\
                            (PS + off_ + src_ * 4),                            \
                        (__attribute__((address_space(3))) unsigned int*)      \
                            (T_ + bq_ * 64),                                   \
                        16, 0, 0);                                             \
                }                                                              \
            }                                                                  \
        } while (0)

    // zero output staging (tail 625..639 must be 0)
    for (int i = t; i < KPAD; i += 256) { SXh[i] = 0; SXl[i] = 0; }

    STAGE(0, 0);   // prologue

    f32x4 acc = {};
    int cur = 0;
    #pragma unroll
    for (int hc = 0; hc < 8; ++hc) {
        __syncthreads();   // buf[cur] staged (vmcnt drained); prev reads done
        if (hc < 7) STAGE(cur ^ 1, hc + 1);   // async loads fly under compute

        const float* Tf1 = (const float*)&Tb[cur][0][0];
        const float* Tf2 = (const float*)&Tb[cur][1][0];
        const int kb = fg * RR + sPos;
        float av[8], bv[8];
        #pragma unroll
        for (int i = 0; i < 8; ++i) {
            av[i] = Tf1[kb + i * RR];
            bv[i] = Tf2[kb + i * RR];
        }
        s16x8 ah, al, bh, bl;
        cvt8(av, ah, al);
        cvt8(bv, bh, bl);
        MM(acc, ah, bh);
        MM(acc, ah, bl);
        MM(acc, al, bh);
        cur ^= 1;
    }
    #undef STAGE

    // Epilogue (verified R9): C/D col = lane&15, row = 4*(lane>>4)+r.
    const int arow = (lane >> 4) * 4;
    if (fr < clsN) {
        const int dy = 2 * (fr / nj) + ci;
        const int dx = 2 * (fr % nj) + cj;
        #pragma unroll
        for (int r = 0; r < 4; ++r) {
            const int rowp = arow + r;
            if (rowp < clsN) {
                const int i1 = 2 * (rowp / nj) + ci;
                const int j1 = 2 * (rowp % nj) + cj;
                const int aidx = enc25(i1, dy) * 25 + enc25(j1, dx);
                unsigned short hh, ll;
                split2(acc[r], hh, ll);
                SXh[aidx] = hh; SXl[aidx] = ll;
            }
        }
    }
    __syncthreads();

    unsigned int* rh = (unsigned int*)(xh + (size_t)cid * KPAD);
    unsigned int* rl = (unsigned int*)(xl + (size_t)cid * KPAD);
    const unsigned int* sh = (const unsigned int*)SXh;
    const unsigned int* sl = (const unsigned int*)SXl;
    for (int i = t; i < KPAD / 2; i += 256) { rh[i] = sh[i]; rl[i] = sl[i]; }
}

// ---------------------------------------------------------------------------
// MFMA GEMM: Y[m,n] = relu( sum_k X[m,k]*W[n,k] + bias[n] )
// X,W as bf16 hi/lo planes; products hh + hl + lh. 64x32 tile, BK=64,
// grid (N/32, M/64) = 512 blocks -> 2 blocks/CU so staging drains overlap
// across blocks. 4 waves (2 M-halves x 2 N-halves), each wave 32x16 =
// 2x1 16x16x32 fragments.
// ---------------------------------------------------------------------------
template<bool SPLIT_OUT>
__global__ __launch_bounds__(256) void gemm_mfma(
    const unsigned short* __restrict__ Xh, const unsigned short* __restrict__ Xl, int ldx,
    const unsigned short* __restrict__ Wh, const unsigned short* __restrict__ Wl, int ldw,
    const float* __restrict__ bias, int K,
    float* __restrict__ Yf, unsigned short* __restrict__ Yh, unsigned short* __restrict__ Yl,
    int ldy)
{
    __shared__ unsigned short As[2][64][72];   // 18.4 KB
    __shared__ unsigned short Bs[2][32][72];   // 9.2 KB

    const int t = threadIdx.x;
    const int m_base = blockIdx.y * 64;
    const int n_base = blockIdx.x * 32;

    const int trow = t >> 2;          // 0..63  (A rows)
    const int tc   = (t & 3) * 8;     // 0,8,16,24
    const int trB  = t >> 3;          // 0..31  (B rows)
    const int tcB  = (t & 7) * 8;     // 0..56

    const unsigned short* xh_p = Xh + (size_t)(m_base + trow) * ldx + tc;
    const unsigned short* xl_p = Xl + (size_t)(m_base + trow) * ldx + tc;
    const unsigned short* wh_p = Wh + (size_t)(n_base + trB) * ldw + tcB;
    const unsigned short* wl_p = Wl + (size_t)(n_base + trB) * ldw + tcB;

    const int wv   = t >> 6;
    const int lane = t & 63;
    const int wr = (wv >> 1) * 32;    // 0 or 32
    const int wc = (wv & 1) * 16;     // 0 or 16
    const int fr = lane & 15;
    const int fg = (lane >> 4) * 8;

    f32x4 acc0 = {}, acc1 = {};

    for (int k0 = 0; k0 < K; k0 += 64) {
        s16x8 vxh0 = *(const s16x8*)(xh_p + k0);
        s16x8 vxh1 = *(const s16x8*)(xh_p + k0 + 32);
        s16x8 vxl0 = *(const s16x8*)(xl_p + k0);
        s16x8 vxl1 = *(const s16x8*)(xl_p + k0 + 32);
        s16x8 vwh  = *(const s16x8*)(wh_p + k0);
        s16x8 vwl  = *(const s16x8*)(wl_p + k0);
        __syncthreads();
        *(s16x8*)&As[0][trow][tc]      = vxh0;
        *(s16x8*)&As[0][trow][tc + 32] = vxh1;
        *(s16x8*)&As[1][trow][tc]      = vxl0;
        *(s16x8*)&As[1][trow][tc + 32] = vxl1;
        *(s16x8*)&Bs[0][trB][tcB]      = vwh;
        *(s16x8*)&Bs[1][trB][tcB]      = vwl;
        __syncthreads();

        #pragma unroll
        for (int ks = 0; ks < 2; ++ks) {
            const int ko = ks * 32 + fg;
            s16x8 ah0 = *(const s16x8*)&As[0][wr + fr][ko];
            s16x8 ah1 = *(const s16x8*)&As[0][wr + 16 + fr][ko];
            s16x8 al0 = *(const s16x8*)&As[1][wr + fr][ko];
            s16x8 al1 = *(const s16x8*)&As[1][wr + 16 + fr][ko];
            s16x8 bh  = *(const s16x8*)&Bs[0][wc + fr][ko];
            s16x8 bl  = *(const s16x8*)&Bs[1][wc + fr][ko];

            MM(acc0, ah0, bh); MM(acc0, ah0, bl); MM(acc0, al0, bh);
            MM(acc1, ah1, bh); MM(acc1, ah1, bl); MM(acc1, al1, bh);
        }
    }

    const int arow = (lane >> 4) * 4;
    const int col = n_base + wc + fr;
    const float bv = bias[col];
    #pragma unroll
    for (int mf = 0; mf < 2; ++mf) {
        const f32x4 a = mf == 0 ? acc0 : acc1;
        #pragma unroll
        for (int r = 0; r < 4; ++r) {
            const int row = m_base + wr + mf * 16 + arow + r;
            float v = fmaxf(a[r] + bv, 0.f);
            if (SPLIT_OUT) {
                unsigned short h, l;
                split2(v, h, l);
                Yh[(size_t)row * ldy + col] = h;
                Yl[(size_t)row * ldy + col] = l;
            } else {
                Yf[(size_t)row * ldy + col] = v;
            }
        }
    }
}

// ---------------------------------------------------------------------------
// Head: out[b,:] = h2[b,:] @ W3.T + b3
// ---------------------------------------------------------------------------
__global__ __launch_bounds__(256) void head_kernel(
    const float* __restrict__ h2, const float* __restrict__ W3,
    const float* __restrict__ b3, float* __restrict__ out)
{
    const int b = blockIdx.x;
    const int t = threadIdx.x;
    const float* row = h2 + (size_t)b * REP_N;

    float a0 = 0.f, a1 = 0.f, a2 = 0.f, a3 = 0.f;
    for (int k = t; k < REP_N; k += 256) {
        float x = row[k];
        a0 = fmaf(x, W3[k],             a0);
        a1 = fmaf(x, W3[REP_N + k],     a1);
        a2 = fmaf(x, W3[2 * REP_N + k], a2);
        a3 = fmaf(x, W3[3 * REP_N + k], a3);
    }
    #pragma unroll
    for (int off = 32; off > 0; off >>= 1) {
        a0 += __shfl_down(a0, off);
        a1 += __shfl_down(a1, off);
        a2 += __shfl_down(a2, off);
        a3 += __shfl_down(a3, off);
    }
    __shared__ float red[4][4];
    int wid = t >> 6, lane = t & 63;
    if (lane == 0) { red[wid][0] = a0; red[wid][1] = a1; red[wid][2] = a2; red[wid][3] = a3; }
    __syncthreads();
    if (t < 4) {
        out[b * 4 + t] = red[0][t] + red[1][t] + red[2][t] + red[3][t] + b3[t];
    }
}

extern "C" void kernel_launch(void* const* d_in, const int* in_sizes, int n_in,
                              void* d_out, int out_size, void* d_ws, size_t ws_size,
                              hipStream_t stream) {
    const float* p1 = (const float*)d_in[0];
    const float* p2 = (const float*)d_in[1];
    const float* W1 = (const float*)d_in[2];
    const float* b1 = (const float*)d_in[3];
    const float* W2 = (const float*)d_in[4];
    const float* b2 = (const float*)d_in[5];
    const float* W3 = (const float*)d_in[6];
    const float* b3 = (const float*)d_in[7];
    float* out = (float*)d_out;

    char* ws = (char*)d_ws;
    unsigned short* xh  = (unsigned short*)(ws + 0);         // 1.31 MB
    unsigned short* xl  = (unsigned short*)(ws + 1310720);   // 1.31 MB
    unsigned short* w1h = (unsigned short*)(ws + 2621440);   // 1.31 MB
    unsigned short* w1l = (unsigned short*)(ws + 3932160);   // 1.31 MB
    float*          h2  = (float*)(ws + 0);                  // 4.19 MB (reuse after GEMM1)
    unsigned short* h1h = (unsigned short*)(ws + 5242880);   // 2.10 MB
    unsigned short* h1l = (unsigned short*)(ws + 7340032);   // 2.10 MB
    unsigned short* w2h = (unsigned short*)(ws + 9437184);   // 2.10 MB
    unsigned short* w2l = (unsigned short*)(ws + 11534336);  // 2.10 MB

    // Fused corr + weight-prep (interleaved block routing)
    corr_prep_kernel<<<4608, 256, 0, stream>>>(
        p1, p2, W1, W2, xh, xl, w1h, w1l, w2h, w2l);

    // GEMM1: h1 = relu(x @ W1g.T + b1), split output planes
    gemm_mfma<true><<<dim3(32, 16), 256, 0, stream>>>(
        xh, xl, KPAD, w1h, w1l, KPAD, b1, KPAD,
        (float*)nullptr, h1h, h1l, REP_N);

    // GEMM2: h2 = relu(h1 @ W2.T + b2), f32 output
    gemm_mfma<false><<<dim3(32, 16), 256, 0, stream>>>(
        h1h, h1l, REP_N, w2h, w2l, REP_N, b2, REP_N,
        h2, (unsigned short*)nullptr, (unsigned short*)nullptr, REP_N);

    head_kernel<<<BATCH, 256, 0, stream>>>(h2, W3, b3, out);
}

// Round 14
// 61.779 us; speedup vs baseline: 1.4974x; 1.0131x over previous
//
#include <hip/hip_runtime.h>

// Problem constants
#define BATCH 1024
#define RR    49        // 7*7 spatial
#define SP    12544     // 256*49 per-batch patch elems; also FLAT
#define KVALID 625      // nonzero correlation outputs per batch
#define KPAD   640      // padded K for GEMM1
#define REP_N  1024

typedef __attribute__((ext_vector_type(4))) float f32x4;
typedef __attribute__((ext_vector_type(8))) short s16x8;   // 8 bf16 (4 VGPRs)

// ---- bf16 split helpers (RNE) ----
__device__ __forceinline__ unsigned short f2bf_rne(float f) {
    unsigned int u = __float_as_uint(f);
    unsigned int r = u + 0x7FFFu + ((u >> 16) & 1u);
    return (unsigned short)(r >> 16);
}
__device__ __forceinline__ float bf2f(unsigned short h) {
    return __uint_as_float(((unsigned int)h) << 16);
}
__device__ __forceinline__ void split2(float v, unsigned short& h, unsigned short& l) {
    h = f2bf_rne(v);
    l = f2bf_rne(v - bf2f(h));
}
// Pack two floats to bf16 pair (verified numerically R4-R13).
__device__ __forceinline__ unsigned int cvtpk_bf16(float a, float b) {
    unsigned int r;
    asm("v_cvt_pk_bf16_f32 %0, %1, %2" : "=v"(r) : "v"(a), "v"(b));
    return r;
}
// Split 8 floats -> hi/lo s16x8 fragments.
__device__ __forceinline__ void cvt8(const float* v, s16x8& hv, s16x8& lv) {
    unsigned int* hp = (unsigned int*)&hv;
    unsigned int* lp = (unsigned int*)&lv;
    #pragma unroll
    for (int i = 0; i < 4; ++i) {
        float v0 = v[2 * i], v1 = v[2 * i + 1];
        unsigned int ph = cvtpk_bf16(v0, v1);
        float h0 = __uint_as_float(ph << 16);
        float h1 = __uint_as_float(ph & 0xFFFF0000u);
        unsigned int pl = cvtpk_bf16(v0 - h0, v1 - h1);
        hp[i] = ph; lp[i] = pl;
    }
}

// Decode index u in [0,25) -> (i, d), i,d in [0,7), i+d even.
__device__ __forceinline__ void dec25(int u, int& i, int& d) {
    int ii = (u >= 4) + (u >= 7) + (u >= 11) + (u >= 14) + (u >= 18) + (u >= 21);
    int cum = (7 * ii + 1) >> 1;
    i = ii;
    d = 2 * (u - cum) + (ii & 1);
}
// Encode (i,d) -> [0,25), inverse of dec25.
__device__ __forceinline__ int enc25(int i, int d) {
    return ((7 * i + 1) >> 1) + ((d - (i & 1)) >> 1);
}

// Compact index a in [0,640) -> flat column into W1's FLAT dim (a>=625 unused).
__device__ __forceinline__ int kflat_of(int a) {
    int ar = a / 25, ac = a % 25;
    int i, dy, j, dx;
    dec25(ar, i, dy);
    dec25(ac, j, dx);
    int pi = (dy + 16 - i) >> 1;
    int pj = (dx + 16 - j) >> 1;
    return (pi * 16 + pj) * 49 + i * 7 + j;
}

#define MM(d, a, b) d = __builtin_amdgcn_mfma_f32_16x16x32_bf16(a, b, d, 0, 0, 0)

// ---------------------------------------------------------------------------
// MEGA kernel: corr (parity Gram, verified R9/R12) + W1/W2 prep fused.
// Block routing (interleaved): bid<2048 even -> corr batch bid/2; odd ->
// W1-prep bid/2; bid>=2048 -> prep 1024+(bid-2048).
// corr: 8 half-chunks (32 ch) double-buffered via global_load_lds width=16
// with COUNTED vmcnt (T4): per phase wait vmcnt(4) — only the current
// buffer's 4 loads — the next buffer's loads STAY IN FLIGHT across the
// barrier. No vmcnt(0) drain until the final phase. Raw s_barrier pairs
// replace __syncthreads.
// ---------------------------------------------------------------------------
__global__ __launch_bounds__(256) void corr_prep_kernel(
    const float* __restrict__ p1, const float* __restrict__ p2,
    const float* __restrict__ W1, const float* __restrict__ W2,
    unsigned short* __restrict__ xh, unsigned short* __restrict__ xl,
    unsigned short* __restrict__ w1h, unsigned short* __restrict__ w1l,
    unsigned short* __restrict__ w2h, unsigned short* __restrict__ w2l)
{
    __shared__ float4 Tb[2][2][512];       // [buf][tensor][8*64] = 32 KB
    __shared__ unsigned short SXh[KPAD];   // compact output staging
    __shared__ unsigned short SXl[KPAD];

    const int bid = blockIdx.x;
    const int t   = threadIdx.x;

    bool isCorr = false;
    int cid = 0, pid = 0;
    if (bid < 2048) {
        if ((bid & 1) == 0) { isCorr = true; cid = bid >> 1; }
        else                { pid = bid >> 1; }
    } else {
        pid = 1024 + (bid - 2048);
    }

    if (!isCorr) {
        // ---- weight prep branch (block-uniform) ----
        if (pid < 2560) {
            int idx = pid * 256 + t;             // over REP_N*KPAD
            int n = idx / KPAD, a = idx - n * KPAD;
            float v = 0.f;
            if (a < KVALID) v = W1[(size_t)n * SP + kflat_of(a)];
            unsigned short h, l;
            split2(v, h, l);
            w1h[idx] = h; w1l[idx] = l;
        } else {
            int idx = ((pid - 2560) * 256 + t) * 4;   // over REP_N*REP_N
            float4 v = *(const float4*)&W2[idx];
            unsigned short h0, l0, h1, l1, h2, l2, h3, l3;
            split2(v.x, h0, l0); split2(v.y, h1, l1);
            split2(v.z, h2, l2); split2(v.w, h3, l3);
            *(ushort4*)&w2h[idx] = make_ushort4(h0, h1, h2, h3);
            *(ushort4*)&w2l[idx] = make_ushort4(l0, l1, l2, l3);
        }
        return;
    }

    // ---- corr branch ----
    const float* P1 = p1 + (size_t)cid * SP;
    const float* P2 = p2 + (size_t)cid * SP;

    const int wv   = t >> 6;
    const int lane = t & 63;
    const int fr   = lane & 15;        // class-pos index (A row / B col)
    const int fg   = (lane >> 4) * 8;  // k-offset within 32-row tile

    // parity-class geometry
    const int ci = wv >> 1, cj = wv & 1;
    const int nj = 4 - cj;
    const int clsN = (4 - ci) * nj;          // 16 / 12 / 12 / 9
    const int pr = (fr < clsN) ? fr : 0;
    const int sPos = (2 * (pr / nj) + ci) * 7 + (2 * (pr % nj) + cj);

    // staging role: waves 0,1 -> p1; waves 2,3 -> p2. Half-chunk = 32ch*49
    // = 1568 floats = 392 float4; each wave issues a UNIFORM 4 loads
    // (regions of 64 float4; bq 6 partial and bq 7 dummy are src-clamped,
    // landing in the LDS pad [392,512)) so vmcnt counts are wave-uniform.
    const float* PS = (wv < 2) ? P1 : P2;
    const int tens  = wv >> 1;
    const int start = (wv & 1) * 4;          // bq range [0,4) or [4,8)

    #define STAGE(buf, hc)                                                     \
        do {                                                                   \
            const int off_ = (hc) * 1568;                                      \
            float4* T_ = &Tb[(buf)][tens][0];                                  \
            _Pragma("unroll")                                                  \
            for (int j_ = 0; j_ < 4; ++j_) {                                   \
                const int bq_  = start + j_;                                   \
                const int src_ = min(bq_ * 64 + lane, 391);                    \
                __builtin_amdgcn_global_load_lds(                              \
                    (const __attribute__((address_space(1))) unsigned int*)    \
                        (PS + off_ + src_ * 4),                                \
                    (__attribute__((address_space(3))) unsigned int*)          \
                        (T_ + bq_ * 64),                                       \
                    16, 0, 0);                                                 \
            }                                                                  \
        } while (0)

    // zero output staging (tail 625..639 must be 0)
    for (int i = t; i < KPAD; i += 256) { SXh[i] = 0; SXl[i] = 0; }

    STAGE(0, 0);   // prologue: 2 stages in flight
    STAGE(1, 1);

    f32x4 acc = {};
    #pragma unroll
    for (int hc = 0; hc < 8; ++hc) {
        // Wait ONLY for the current buffer's 4 loads (oldest in the queue);
        // the next buffer's 4 remain outstanding across the barrier.
        if (hc < 7) asm volatile("s_waitcnt vmcnt(4)" ::: "memory");
        else        asm volatile("s_waitcnt vmcnt(0)" ::: "memory");
        __builtin_amdgcn_s_barrier();          // all waves' current loads landed
        __builtin_amdgcn_sched_barrier(0);     // pin: no ds_read hoisted above

        const int cur = hc & 1;
        const float* Tf1 = (const float*)&Tb[cur][0][0];
        const float* Tf2 = (const float*)&Tb[cur][1][0];
        const int kb = fg * RR + sPos;
        float av[8], bv[8];
        #pragma unroll
        for (int i = 0; i < 8; ++i) {
            av[i] = Tf1[kb + i * RR];
            bv[i] = Tf2[kb + i * RR];
        }
        s16x8 ah, al, bh, bl;
        cvt8(av, ah, al);
        cvt8(bv, bh, bl);
        MM(acc, ah, bh);
        MM(acc, ah, bl);
        MM(acc, al, bh);

        __builtin_amdgcn_sched_barrier(0);
        __builtin_amdgcn_s_barrier();          // all waves done reading buf[cur]
        if (hc < 6) STAGE(cur, hc + 2);        // refill the buffer just freed
    }
    #undef STAGE

    // Epilogue (verified R9): C/D col = lane&15, row = 4*(lane>>4)+r.
    const int arow = (lane >> 4) * 4;
    if (fr < clsN) {
        const int dy = 2 * (fr / nj) + ci;
        const int dx = 2 * (fr % nj) + cj;
        #pragma unroll
        for (int r = 0; r < 4; ++r) {
            const int rowp = arow + r;
            if (rowp < clsN) {
                const int i1 = 2 * (rowp / nj) + ci;
                const int j1 = 2 * (rowp % nj) + cj;
                const int aidx = enc25(i1, dy) * 25 + enc25(j1, dx);
                unsigned short hh, ll;
                split2(acc[r], hh, ll);
                SXh[aidx] = hh; SXl[aidx] = ll;
            }
        }
    }
    __syncthreads();

    unsigned int* rh = (unsigned int*)(xh + (size_t)cid * KPAD);
    unsigned int* rl = (unsigned int*)(xl + (size_t)cid * KPAD);
    const unsigned int* sh = (const unsigned int*)SXh;
    const unsigned int* sl = (const unsigned int*)SXl;
    for (int i = t; i < KPAD / 2; i += 256) { rh[i] = sh[i]; rl[i] = sl[i]; }
}

// ---------------------------------------------------------------------------
// MFMA GEMM: Y[m,n] = relu( sum_k X[m,k]*W[n,k] + bias[n] )
// X,W as bf16 hi/lo planes; products hh + hl + lh. 64x32 tile, BK=64,
// grid (N/32, M/64) = 512 blocks -> 2 blocks/CU. 4 waves, each 32x16.
// ---------------------------------------------------------------------------
template<bool SPLIT_OUT>
__global__ __launch_bounds__(256) void gemm_mfma(
    const unsigned short* __restrict__ Xh, const unsigned short* __restrict__ Xl, int ldx,
    const unsigned short* __restrict__ Wh, const unsigned short* __restrict__ Wl, int ldw,
    const float* __restrict__ bias, int K,
    float* __restrict__ Yf, unsigned short* __restrict__ Yh, unsigned short* __restrict__ Yl,
    int ldy)
{
    __shared__ unsigned short As[2][64][72];   // 18.4 KB
    __shared__ unsigned short Bs[2][32][72];   // 9.2 KB

    const int t = threadIdx.x;
    const int m_base = blockIdx.y * 64;
    const int n_base = blockIdx.x * 32;

    const int trow = t >> 2;          // 0..63  (A rows)
    const int tc   = (t & 3) * 8;     // 0,8,16,24
    const int trB  = t >> 3;          // 0..31  (B rows)
    const int tcB  = (t & 7) * 8;     // 0..56

    const unsigned short* xh_p = Xh + (size_t)(m_base + trow) * ldx + tc;
    const unsigned short* xl_p = Xl + (size_t)(m_base + trow) * ldx + tc;
    const unsigned short* wh_p = Wh + (size_t)(n_base + trB) * ldw + tcB;
    const unsigned short* wl_p = Wl + (size_t)(n_base + trB) * ldw + tcB;

    const int wv   = t >> 6;
    const int lane = t & 63;
    const int wr = (wv >> 1) * 32;    // 0 or 32
    const int wc = (wv & 1) * 16;     // 0 or 16
    const int fr = lane & 15;
    const int fg = (lane >> 4) * 8;

    f32x4 acc0 = {}, acc1 = {};

    for (int k0 = 0; k0 < K; k0 += 64) {
        s16x8 vxh0 = *(const s16x8*)(xh_p + k0);
        s16x8 vxh1 = *(const s16x8*)(xh_p + k0 + 32);
        s16x8 vxl0 = *(const s16x8*)(xl_p + k0);
        s16x8 vxl1 = *(const s16x8*)(xl_p + k0 + 32);
        s16x8 vwh  = *(const s16x8*)(wh_p + k0);
        s16x8 vwl  = *(const s16x8*)(wl_p + k0);
        __syncthreads();
        *(s16x8*)&As[0][trow][tc]      = vxh0;
        *(s16x8*)&As[0][trow][tc + 32] = vxh1;
        *(s16x8*)&As[1][trow][tc]      = vxl0;
        *(s16x8*)&As[1][trow][tc + 32] = vxl1;
        *(s16x8*)&Bs[0][trB][tcB]      = vwh;
        *(s16x8*)&Bs[1][trB][tcB]      = vwl;
        __syncthreads();

        #pragma unroll
        for (int ks = 0; ks < 2; ++ks) {
            const int ko = ks * 32 + fg;
            s16x8 ah0 = *(const s16x8*)&As[0][wr + fr][ko];
            s16x8 ah1 = *(const s16x8*)&As[0][wr + 16 + fr][ko];
            s16x8 al0 = *(const s16x8*)&As[1][wr + fr][ko];
            s16x8 al1 = *(const s16x8*)&As[1][wr + 16 + fr][ko];
            s16x8 bh  = *(const s16x8*)&Bs[0][wc + fr][ko];
            s16x8 bl  = *(const s16x8*)&Bs[1][wc + fr][ko];

            MM(acc0, ah0, bh); MM(acc0, ah0, bl); MM(acc0, al0, bh);
            MM(acc1, ah1, bh); MM(acc1, ah1, bl); MM(acc1, al1, bh);
        }
    }

    const int arow = (lane >> 4) * 4;
    const int col = n_base + wc + fr;
    const float bv = bias[col];
    #pragma unroll
    for (int mf = 0; mf < 2; ++mf) {
        const f32x4 a = mf == 0 ? acc0 : acc1;
        #pragma unroll
        for (int r = 0; r < 4; ++r) {
            const int row = m_base + wr + mf * 16 + arow + r;
            float v = fmaxf(a[r] + bv, 0.f);
            if (SPLIT_OUT) {
                unsigned short h, l;
                split2(v, h, l);
                Yh[(size_t)row * ldy + col] = h;
                Yl[(size_t)row * ldy + col] = l;
            } else {
                Yf[(size_t)row * ldy + col] = v;
            }
        }
    }
}

// ---------------------------------------------------------------------------
// Head: out[b,:] = h2[b,:] @ W3.T + b3
// ---------------------------------------------------------------------------
__global__ __launch_bounds__(256) void head_kernel(
    const float* __restrict__ h2, const float* __restrict__ W3,
    const float* __restrict__ b3, float* __restrict__ out)
{
    const int b = blockIdx.x;
    const int t = threadIdx.x;
    const float* row = h2 + (size_t)b * REP_N;

    float a0 = 0.f, a1 = 0.f, a2 = 0.f, a3 = 0.f;
    for (int k = t; k < REP_N; k += 256) {
        float x = row[k];
        a0 = fmaf(x, W3[k],             a0);
        a1 = fmaf(x, W3[REP_N + k],     a1);
        a2 = fmaf(x, W3[2 * REP_N + k], a2);
        a3 = fmaf(x, W3[3 * REP_N + k], a3);
    }
    #pragma unroll
    for (int off = 32; off > 0; off >>= 1) {
        a0 += __shfl_down(a0, off);
        a1 += __shfl_down(a1, off);
        a2 += __shfl_down(a2, off);
        a3 += __shfl_down(a3, off);
    }
    __shared__ float red[4][4];
    int wid = t >> 6, lane = t & 63;
    if (lane == 0) { red[wid][0] = a0; red[wid][1] = a1; red[wid][2] = a2; red[wid][3] = a3; }
    __syncthreads();
    if (t < 4) {
        out[b * 4 + t] = red[0][t] + red[1][t] + red[2][t] + red[3][t] + b3[t];
    }
}

extern "C" void kernel_launch(void* const* d_in, const int* in_sizes, int n_in,
                              void* d_out, int out_size, void* d_ws, size_t ws_size,
                              hipStream_t stream) {
    const float* p1 = (const float*)d_in[0];
    const float* p2 = (const float*)d_in[1];
    const float* W1 = (const float*)d_in[2];
    const float* b1 = (const float*)d_in[3];
    const float* W2 = (const float*)d_in[4];
    const float* b2 = (const float*)d_in[5];
    const float* W3 = (const float*)d_in[6];
    const float* b3 = (const float*)d_in[7];
    float* out = (float*)d_out;

    char* ws = (char*)d_ws;
    unsigned short* xh  = (unsigned short*)(ws + 0);         // 1.31 MB
    unsigned short* xl  = (unsigned short*)(ws + 1310720);   // 1.31 MB
    unsigned short* w1h = (unsigned short*)(ws + 2621440);   // 1.31 MB
    unsigned short* w1l = (unsigned short*)(ws + 3932160);   // 1.31 MB
    float*          h2  = (float*)(ws + 0);                  // 4.19 MB (reuse after GEMM1)
    unsigned short* h1h = (unsigned short*)(ws + 5242880);   // 2.10 MB
    unsigned short* h1l = (unsigned short*)(ws + 7340032);   // 2.10 MB
    unsigned short* w2h = (unsigned short*)(ws + 9437184);   // 2.10 MB
    unsigned short* w2l = (unsigned short*)(ws + 11534336);  // 2.10 MB

    // Fused corr + weight-prep (interleaved block routing, counted-vmcnt corr)
    corr_prep_kernel<<<4608, 256, 0, stream>>>(
        p1, p2, W1, W2, xh, xl, w1h, w1l, w2h, w2l);

    // GEMM1: h1 = relu(x @ W1g.T + b1), split output planes
    gemm_mfma<true><<<dim3(32, 16), 256, 0, stream>>>(
        xh, xl, KPAD, w1h, w1l, KPAD, b1, KPAD,
        (float*)nullptr, h1h, h1l, REP_N);

    // GEMM2: h2 = relu(h1 @ W2.T + b2), f32 output
    gemm_mfma<false><<<dim3(32, 16), 256, 0, stream>>>(
        h1h, h1l, REP_N, w2h, w2l, REP_N, b2, REP_N,
        h2, (unsigned short*)nullptr, (unsigned short*)nullptr, REP_N);

    head_kernel<<<BATCH, 256, 0, stream>>>(h2, W3, b3, out);
}